// Round 3
// baseline (511.895 us; speedup 1.0000x reference)
//
#include <hip/hip_runtime.h>
#include <cstddef>

typedef unsigned short ushort_t;
typedef __attribute__((ext_vector_type(8))) short bf16x8;
typedef __attribute__((ext_vector_type(4))) float f32x4;

// ---------------- workspace layout (float offsets) ----------------
// [0..1048576): p0 (4096x256) -> dots (1024x1024) -> bitmap (524288 words, 2MB)
#define WS_P0     0u
#define WS_DOTS   0u
#define WS_BITMAP 0u
#define WS_HN0    1048576u   /* 4096x256; -> hc (6144x128) at the end */
#define WS_HC     1048576u
#define WS_H1     2097152u   /* 4096x128 */
#define WS_H1N    2621440u   /* 4096x128 */
#define WS_P1     3145728u   /* 4096x128; -> xt (bf16 128x6144 = 393216 f) */
#define WS_XT     3145728u
#define WS_HN1    3670016u   /* 4096x128; -> sqn (1024) after h2 gemm */
#define WS_SQN    3670016u
#define WS_H2     4194304u   /* 4096x128 */
#define WS_X      4718592u   /* 6144x128 */
#define WS_OB     5505024u   /* bf16 6144x128 = 393216 floats */
// ---- contiguous zero region (one memset): ----
#define WS_NEIGH  6291456u   /* 786432 */
#define WS_ROWSUM 7077888u   /* 6144 */
#define WS_SCAL   7084032u   /* 16: [S_all, s1, cnt, sub] */
#define WS_DEG    7084048u   /* int 4096 */
// ---- end zero region ----
#define WS_NN     7088144u   /* int 1024 */
#define WS_CUR    7089168u   /* int 4096 */
#define WS_ROWPTR 7093264u   /* int 4097 */
#define WS_EIDX   7097361u   /* int 69632 */

__device__ inline ushort_t f2bf(float f) {
  unsigned u = __float_as_uint(f);
  u += 0x7fff + ((u >> 16) & 1);   // round-to-nearest-even
  return (ushort_t)(u >> 16);
}

// ---------------- generic NT GEMM: C = act(A@B^T (+ A2@B2^T) + bias) -------
// grid = (N/64, M/64), block = 256. Optional: bf16 output (Cb), A2-row scale
// a2 /= (a2scale[row]+1)  (folds the neigh/(rowsum+1) divide into the gemm).
__global__ __launch_bounds__(256, 2) void gemm_nt(
    const float* __restrict__ A, int lda,
    const float* __restrict__ B, int ldb,
    const float* __restrict__ A2, int lda2,
    const float* __restrict__ B2, int ldb2,
    const float* __restrict__ bias,
    float* __restrict__ C, int ldc,
    int K, int relu,
    ushort_t* __restrict__ Cb,
    const float* __restrict__ a2scale)
{
  __shared__ float As[16][68];
  __shared__ float Bs[16][68];
  const int tid = threadIdx.x;
  const int tx = tid & 15, ty = tid >> 4;
  const int lr = tid >> 2;
  const int lk = (tid & 3) << 2;
  const int i0 = blockIdx.y << 6;
  const int j0 = blockIdx.x << 6;
  float acc[4][4] = {};
  const int npass = (A2 != nullptr) ? 2 : 1;
  for (int pass = 0; pass < npass; ++pass) {
    const float* Ap = pass ? A2 : A; const int la = pass ? lda2 : lda;
    const float* Bp = pass ? B2 : B; const int lb = pass ? ldb2 : ldb;
    const float sc = (pass && a2scale) ? __frcp_rn(a2scale[i0 + lr] + 1.f) : 1.f;
    for (int k0 = 0; k0 < K; k0 += 16) {
      float4 ag = *(const float4*)(Ap + (size_t)(i0 + lr) * la + (k0 + lk));
      const float4 bg = *(const float4*)(Bp + (size_t)(j0 + lr) * lb + (k0 + lk));
      ag.x *= sc; ag.y *= sc; ag.z *= sc; ag.w *= sc;
      __syncthreads();
      As[lk+0][lr]=ag.x; As[lk+1][lr]=ag.y; As[lk+2][lr]=ag.z; As[lk+3][lr]=ag.w;
      Bs[lk+0][lr]=bg.x; Bs[lk+1][lr]=bg.y; Bs[lk+2][lr]=bg.z; Bs[lk+3][lr]=bg.w;
      __syncthreads();
#pragma unroll
      for (int k = 0; k < 16; ++k) {
        const float4 a4 = *(const float4*)&As[k][ty << 2];
        const float4 b4 = *(const float4*)&Bs[k][tx << 2];
        const float aa[4] = {a4.x, a4.y, a4.z, a4.w};
        const float bb[4] = {b4.x, b4.y, b4.z, b4.w};
#pragma unroll
        for (int ii = 0; ii < 4; ++ii)
#pragma unroll
          for (int jj = 0; jj < 4; ++jj)
            acc[ii][jj] += aa[ii] * bb[jj];
      }
    }
  }
  float badd[4] = {0.f, 0.f, 0.f, 0.f};
  if (bias) {
    const float4 t = *(const float4*)(bias + j0 + (tx << 2));
    badd[0]=t.x; badd[1]=t.y; badd[2]=t.z; badd[3]=t.w;
  }
#pragma unroll
  for (int ii = 0; ii < 4; ++ii) {
    float4 o;
    o.x = acc[ii][0] + badd[0];
    o.y = acc[ii][1] + badd[1];
    o.z = acc[ii][2] + badd[2];
    o.w = acc[ii][3] + badd[3];
    if (relu) { o.x=fmaxf(o.x,0.f); o.y=fmaxf(o.y,0.f); o.z=fmaxf(o.z,0.f); o.w=fmaxf(o.w,0.f); }
    const size_t off = (size_t)(i0 + (ty<<2) + ii) * ldc + j0 + (tx<<2);
    if (Cb) {
      ushort4 ob4;
      ob4.x = f2bf(o.x); ob4.y = f2bf(o.y); ob4.z = f2bf(o.z); ob4.w = f2bf(o.w);
      *(ushort4*)(Cb + off) = ob4;
    } else {
      *(float4*)(C + off) = o;
    }
  }
}

// ---------------- CSR build (bucket edges by dst) ----------------
__global__ void count_k(const int* __restrict__ dst, int* __restrict__ deg, int E) {
  const int e = blockIdx.x * 256 + threadIdx.x;
  if (e < E) atomicAdd(&deg[dst[e]], 1);
}

__global__ __launch_bounds__(1024) void scan_k(const int* __restrict__ deg,
                                               int* __restrict__ rowptr,
                                               int* __restrict__ cursor) {
  __shared__ int sums[1024];
  const int t = threadIdx.x;
  const int4 d = *(const int4*)(deg + (t << 2));
  const int local = d.x + d.y + d.z + d.w;
  sums[t] = local;
  __syncthreads();
  for (int off = 1; off < 1024; off <<= 1) {
    int v = (t >= off) ? sums[t - off] : 0;
    __syncthreads();
    sums[t] += v;
    __syncthreads();
  }
  const int excl = sums[t] - local;
  const int o0 = excl, o1 = o0 + d.x, o2 = o1 + d.y, o3 = o2 + d.z;
  rowptr[(t<<2)+0]=o0; rowptr[(t<<2)+1]=o1; rowptr[(t<<2)+2]=o2; rowptr[(t<<2)+3]=o3;
  cursor[(t<<2)+0]=o0; cursor[(t<<2)+1]=o1; cursor[(t<<2)+2]=o2; cursor[(t<<2)+3]=o3;
  if (t == 1023) rowptr[4096] = sums[1023];
}

__global__ void fill_k(const int* __restrict__ src, const int* __restrict__ dst,
                       int* __restrict__ cursor, int* __restrict__ eidx, int E) {
  const int e = blockIdx.x * 256 + threadIdx.x;
  if (e < E) {
    const int p = atomicAdd(&cursor[dst[e]], 1);
    eidx[p] = src[e];
  }
}

// segment_max as CSR gather. p >= 0 (relu'd) and every segment non-empty
// (self-loops), so init 0 reproduces the isfinite->0 semantics exactly.
__global__ void segmax_k(const float* __restrict__ p, const int* __restrict__ rowptr,
                         const int* __restrict__ eidx, float* __restrict__ hn, int F) {
  const int row = blockIdx.x, f = threadIdx.x;  // blockDim == F
  const int b = rowptr[row], e = rowptr[row + 1];
  float m = 0.f;
  for (int k = b; k < e; ++k) m = fmaxf(m, p[(size_t)eidx[k] * F + f]);
  hn[(size_t)row * F + f] = m;
}

// ---------------- small fused elementwise / reductions ----------------
__device__ inline float wave_sum(float v) {
#pragma unroll
  for (int o = 32; o > 0; o >>= 1) v += __shfl_down(v, o, 64);
  return v;
}

__global__ void relu_l2norm_k(const float* __restrict__ in, float* __restrict__ out) {
  const int row = blockIdx.x, f = threadIdx.x;  // 128 threads
  const float v = fmaxf(in[(size_t)row * 128 + f], 0.f);
  const float ss = wave_sum(v * v);
  __shared__ float w[2];
  if ((f & 63) == 0) w[f >> 6] = ss;
  __syncthreads();
  const float denom = fmaxf(sqrtf(w[0] + w[1]), 1e-12f);
  out[(size_t)row * 128 + f] = v / denom;
}

__global__ void sqn_k(const float* __restrict__ h2, float* __restrict__ sqn) {
  const int row = blockIdx.x, f = threadIdx.x;  // 128 threads
  const float v = h2[(size_t)row * 128 + f];
  const float ss = wave_sum(v * v);
  __shared__ float w[2];
  if ((f & 63) == 0) w[f >> 6] = ss;
  __syncthreads();
  if (f == 0) sqn[row] = w[0] + w[1];
}

// nearest neighbor (excluding self), tie-break smallest index = stable argsort pos 1
__global__ void argmin_k(const float* __restrict__ dots, const float* __restrict__ sqn,
                         int* __restrict__ nn) {
  const int i = blockIdx.x, tid = threadIdx.x;  // 256 threads
  float best = 3.402823466e38f; int bidx = 0x7fffffff;
  const float si = sqn[i];
  for (int j = tid; j < 1024; j += 256) {
    if (j == i) continue;
    float d2 = si + sqn[j] - 2.f * dots[(size_t)i * 1024 + j];
    d2 = fmaxf(d2, 0.f);
    if (d2 < best || (d2 == best && j < bidx)) { best = d2; bidx = j; }
  }
  __shared__ float bv[256]; __shared__ int bi[256];
  bv[tid] = best; bi[tid] = bidx;
  __syncthreads();
  for (int s = 128; s > 0; s >>= 1) {
    if (tid < s) {
      if (bv[tid+s] < bv[tid] || (bv[tid+s] == bv[tid] && bi[tid+s] < bi[tid])) {
        bv[tid] = bv[tid+s]; bi[tid] = bi[tid+s];
      }
    }
    __syncthreads();
  }
  if (tid == 0) nn[i] = bi[0];
}

__global__ void build_x_k(const float* __restrict__ h2, const int* __restrict__ nn,
                          const float* __restrict__ gaps, float* __restrict__ x) {
  const int row = blockIdx.x, f = threadIdx.x;  // 128 threads, grid 6144
  if (row < 4096) {
    x[(size_t)row * 128 + f] = h2[(size_t)row * 128 + f];
  } else {
    const int s = row - 4096, i = s >> 1, r = s & 1;
    const float g = gaps[(i << 1) + r];
    const float c  = h2[(size_t)i * 128 + f];
    const float cn = h2[(size_t)nn[i] * 128 + f];
    x[(size_t)row * 128 + f] = c + g * (cn - c);
  }
}

// x (6144x128 f32) -> xt (128x6144 bf16), 64x64 LDS tile transpose
__global__ void conv_xt_k(const float* __restrict__ x, ushort_t* __restrict__ xt) {
  __shared__ ushort_t t[64][65];
  const int i0 = blockIdx.x << 6, c0 = blockIdx.y << 6;
  const int il = threadIdx.x & 63, rl = threadIdx.x >> 6;
#pragma unroll
  for (int rr = 0; rr < 16; ++rr) {
    const int r = (rr << 2) + rl;
    t[r][il] = f2bf(x[(size_t)(i0 + r) * 128 + c0 + il]);
  }
  __syncthreads();
#pragma unroll
  for (int rr = 0; rr < 16; ++rr) {
    const int c = (rr << 2) + rl;
    xt[(size_t)(c0 + c) * 6144 + i0 + il] = t[il][c];
  }
}

// ---------------- sparse loss correction over edge cells ----------------
// For each DISTINCT adj-nonzero cell (dst,src): claim via bitmap atomicOr, then
// s1 += (sg-1)^2, sub += sg^2, cnt += 1  (sg from the same bf16 rows the dense
// pass used). Dense pass only computes S_all = sum sg^2 -> s0 = S_all - sub.
__global__ __launch_bounds__(256) void edge_claim_k(
    const int* __restrict__ src, const int* __restrict__ dst,
    const ushort_t* __restrict__ ob, unsigned* __restrict__ bitmap,
    float* __restrict__ scal, int E)
{
  __shared__ float part[3];
  const int tid = threadIdx.x;
  if (tid < 3) part[tid] = 0.f;
  __syncthreads();
  const int lane = tid & 63;
  const int nw = gridDim.x << 2;
  float p1 = 0.f, psub = 0.f, pcnt = 0.f;
  for (int e = (blockIdx.x << 2) + (tid >> 6); e < E; e += nw) {
    const int d_ = dst[e], s_ = src[e];
    const unsigned cell = ((unsigned)d_ << 12) + (unsigned)s_;
    int claimed = 0;
    if (lane == 0) {
      const unsigned bit = 1u << (cell & 31);
      const unsigned old = atomicOr(&bitmap[cell >> 5], bit);
      claimed = !(old & bit);
    }
    claimed = __shfl(claimed, 0, 64);
    if (!claimed) continue;
    const unsigned a = *(const unsigned*)(ob + ((size_t)d_ << 7) + (lane << 1));
    const unsigned b = *(const unsigned*)(ob + ((size_t)s_ << 7) + (lane << 1));
    const float a0 = __uint_as_float(a << 16), a1 = __uint_as_float(a & 0xffff0000u);
    const float b0 = __uint_as_float(b << 16), b1 = __uint_as_float(b & 0xffff0000u);
    float v = a0 * b0 + a1 * b1;
    v = wave_sum(v);
    if (lane == 0) {
      const float sg = 1.f / (1.f + __expf(-v));
      p1 += (sg - 1.f) * (sg - 1.f);
      psub += sg * sg;
      pcnt += 1.f;
    }
  }
  if (lane == 0) {
    atomicAdd(&part[0], p1); atomicAdd(&part[1], psub); atomicAdd(&part[2], pcnt);
  }
  __syncthreads();
  if (tid == 0) {
    atomicAdd(&scal[1], part[0]);
    atomicAdd(&scal[3], part[1]);
    atomicAdd(&scal[2], part[2]);
  }
}

// ---------------- fused MFMA: sigmoid(out@out^T) -> S_all + threshold @ x ----
// grid = (96, 8), block 256 (4 waves). No adj reads at all; ob/xt are
// L2-resident (1.5 MB each). Wave w owns i-rows [w*16,w*16+16) and its own P
// rows in LDS -> zero barriers in the j-loop.
__global__ __launch_bounds__(256, 4) void fused_mfma(
    const ushort_t* __restrict__ ob,   // 6144x128 bf16 (out)
    const ushort_t* __restrict__ xt,   // 128x6144 bf16 (x transposed)
    float* __restrict__ neigh,         // 6144x128, pre-zeroed
    float* __restrict__ rowsum,        // 6144, pre-zeroed
    float* __restrict__ scal,          // [S_all, s1, cnt, sub], pre-zeroed
    int njt)
{
  __shared__ ushort_t P[64][72];       // row stride 144B -> 16B aligned b128 reads
  __shared__ float red[256];
  const int tid = threadIdx.x;
  const int w = tid >> 6, lane = tid & 63;
  const int lo = lane & 15, hi = lane >> 4;
  const int i0 = blockIdx.x << 6;
  const int iw = i0 + (w << 4);
  const int jt0 = blockIdx.y * njt;

  bf16x8 ao[4];
  {
    const ushort_t* ap = ob + (size_t)(iw + lo) * 128 + (hi << 3);
#pragma unroll
    for (int kk = 0; kk < 4; ++kk) ao[kk] = *(const bf16x8*)(ap + (kk << 5));
  }
  f32x4 oacc[8];
#pragma unroll
  for (int s = 0; s < 8; ++s) oacc[s] = (f32x4){0.f, 0.f, 0.f, 0.f};
  float s_all = 0.f;
  float rs[4] = {0.f, 0.f, 0.f, 0.f};

  for (int jt = 0; jt < njt; ++jt) {
    const int j0 = (jt0 + jt) << 6;
    // ---- S = out_i @ out_j^T (16 MFMA / wave) ----
    f32x4 sacc[4];
#pragma unroll
    for (int c = 0; c < 4; ++c) sacc[c] = (f32x4){0.f, 0.f, 0.f, 0.f};
#pragma unroll
    for (int c = 0; c < 4; ++c) {
      const ushort_t* bp = ob + (size_t)(j0 + (c << 4) + lo) * 128 + (hi << 3);
#pragma unroll
      for (int kk = 0; kk < 4; ++kk) {
        const bf16x8 b = *(const bf16x8*)(bp + (kk << 5));
        sacc[c] = __builtin_amdgcn_mfma_f32_16x16x32_bf16(ao[kk], b, sacc[c], 0, 0, 0);
      }
    }
    // ---- epilogue: sigmoid, S_all partial, threshold -> P (LDS) ----
    const bool aj = (i0 < 4096) && (j0 < 4096);
#pragma unroll
    for (int c = 0; c < 4; ++c) {
#pragma unroll
      for (int r = 0; r < 4; ++r) {
        const float sg = 1.f / (1.f + __expf(-sacc[c][r]));
        if (aj) s_all += sg * sg;
        const float t = (sg >= 0.5f) ? sg : 0.f;
        rs[r] += t;
        P[(w << 4) + (hi << 2) + r][(c << 4) + lo] = f2bf(t);
      }
    }
    // ---- neigh partial: oacc += P @ x_j (16 MFMA / wave), wave-private P ----
    const bf16x8 pa0 = *(const bf16x8*)&P[(w << 4) + lo][hi << 3];
    const bf16x8 pa1 = *(const bf16x8*)&P[(w << 4) + lo][32 + (hi << 3)];
#pragma unroll
    for (int s = 0; s < 8; ++s) {
      const ushort_t* xp = xt + (size_t)((s << 4) + lo) * 6144 + j0 + (hi << 3);
      const bf16x8 xb0 = *(const bf16x8*)xp;
      const bf16x8 xb1 = *(const bf16x8*)(xp + 32);
      oacc[s] = __builtin_amdgcn_mfma_f32_16x16x32_bf16(pa0, xb0, oacc[s], 0, 0, 0);
      oacc[s] = __builtin_amdgcn_mfma_f32_16x16x32_bf16(pa1, xb1, oacc[s], 0, 0, 0);
    }
  }
  // ---- rowsum: reduce rs over the 16 lanes of each quad-group ----
#pragma unroll
  for (int r = 0; r < 4; ++r) {
    float v = rs[r];
#pragma unroll
    for (int m = 1; m < 16; m <<= 1) v += __shfl_xor(v, m, 64);
    if (lo == 0) atomicAdd(&rowsum[iw + (hi << 2) + r], v);
  }
  // ---- neigh flush (8 j-chunks accumulate) ----
#pragma unroll
  for (int s = 0; s < 8; ++s)
#pragma unroll
    for (int r = 0; r < 4; ++r)
      atomicAdd(&neigh[(size_t)(iw + (hi << 2) + r) * 128 + (s << 4) + lo], oacc[s][r]);
  // ---- S_all block reduction ----
  red[tid] = s_all; __syncthreads();
  for (int s = 128; s > 0; s >>= 1) { if (tid < s) red[tid] += red[tid + s]; __syncthreads(); }
  if (tid == 0) atomicAdd(&scal[0], red[0]);
}

// logits + y + final loss in one launch
__global__ void logits_y_loss_k(const float* __restrict__ hc, const float* __restrict__ Wclf,
                                const float* __restrict__ bclf, const int* __restrict__ labels,
                                const float* __restrict__ scal, float* __restrict__ outp) {
  const int i = blockIdx.x, f = threadIdx.x;  // 128 threads
  const float h = hc[(size_t)i * 128 + f];
  const float v0 = wave_sum(h * Wclf[f]);
  const float v1 = wave_sum(h * Wclf[128 + f]);
  __shared__ float w0[2], w1[2];
  if ((f & 63) == 0) { w0[f >> 6] = v0; w1[f >> 6] = v1; }
  __syncthreads();
  if (f == 0) {
    outp[(size_t)i * 2 + 0] = w0[0] + w0[1] + bclf[0];
    outp[(size_t)i * 2 + 1] = w1[0] + w1[1] + bclf[1];
    outp[12288 + i] = (i < 4096) ? (float)labels[i] : 1.f;
    if (i == 0) {
      const float cnt = scal[2];
      const float neg_w = cnt / (16777216.f - cnt);
      outp[18432] = neg_w * (scal[0] - scal[3]) + scal[1];
    }
  }
}

// ---------------- launcher ----------------
extern "C" void kernel_launch(void* const* d_in, const int* in_sizes, int n_in,
                              void* d_out, int out_size, void* d_ws, size_t ws_size,
                              hipStream_t stream) {
  const float* feat     = (const float*)d_in[0];
  const int*   src      = (const int*)d_in[2];
  const int*   dst      = (const int*)d_in[3];
  const int*   labels   = (const int*)d_in[4];
  const float* W_pool0  = (const float*)d_in[5];
  const float* b_pool0  = (const float*)d_in[6];
  const float* W_self0  = (const float*)d_in[7];
  const float* W_neigh0 = (const float*)d_in[8];
  const float* b0       = (const float*)d_in[9];
  const float* W_pool1  = (const float*)d_in[10];
  const float* b_pool1  = (const float*)d_in[11];
  const float* W_self1  = (const float*)d_in[12];
  const float* W_neigh1 = (const float*)d_in[13];
  const float* b1       = (const float*)d_in[14];
  const float* de_w     = (const float*)d_in[15];
  const float* W_conv   = (const float*)d_in[16];
  const float* W_clf    = (const float*)d_in[17];
  const float* b_clf    = (const float*)d_in[18];
  const float* gaps     = (const float*)d_in[19];
  const int E = in_sizes[2];  // 69632 (E + self-loops)

  float* ws = (float*)d_ws;
  float* p0       = ws + WS_P0;
  float* dots     = ws + WS_DOTS;
  unsigned* bitmap= (unsigned*)(ws + WS_BITMAP);
  float* hn0      = ws + WS_HN0;
  float* hc       = ws + WS_HC;
  float* h1       = ws + WS_H1;
  float* h1n      = ws + WS_H1N;
  float* p1       = ws + WS_P1;
  ushort_t* xt    = (ushort_t*)(ws + WS_XT);
  float* hn1      = ws + WS_HN1;
  float* sqn      = ws + WS_SQN;
  float* h2       = ws + WS_H2;
  float* x        = ws + WS_X;
  ushort_t* ob    = (ushort_t*)(ws + WS_OB);
  float* neigh    = ws + WS_NEIGH;
  float* rowsum   = ws + WS_ROWSUM;
  float* scal     = ws + WS_SCAL;
  int* deg        = (int*)(ws + WS_DEG);
  int* nn         = (int*)(ws + WS_NN);
  int* cursor     = (int*)(ws + WS_CUR);
  int* rowptr     = (int*)(ws + WS_ROWPTR);
  int* eidx       = (int*)(ws + WS_EIDX);

  float* outp = (float*)d_out;
  const dim3 blk(256);

  // one contiguous zero region: neigh + rowsum + scal + deg
  hipMemsetAsync(neigh, 0, (size_t)(WS_DEG + 4096 - WS_NEIGH) * 4, stream);

  // CSR bucket-by-dst
  count_k<<<(E + 255) / 256, blk, 0, stream>>>(dst, deg, E);
  scan_k<<<1, 1024, 0, stream>>>(deg, rowptr, cursor);
  fill_k<<<(E + 255) / 256, blk, 0, stream>>>(src, dst, cursor, eidx, E);

  // layer 0
  gemm_nt<<<dim3(4, 64), blk, 0, stream>>>(feat, 256, W_pool0, 256,
                                           nullptr, 0, nullptr, 0,
                                           b_pool0, p0, 256, 256, 1, nullptr, nullptr);
  segmax_k<<<4096, 256, 0, stream>>>(p0, rowptr, eidx, hn0, 256);
  gemm_nt<<<dim3(2, 64), blk, 0, stream>>>(feat, 256, W_self0, 256,
                                           hn0, 256, W_neigh0, 256,
                                           b0, h1, 128, 256, 0, nullptr, nullptr);
  relu_l2norm_k<<<4096, 128, 0, stream>>>(h1, h1n);

  // layer 1
  gemm_nt<<<dim3(2, 64), blk, 0, stream>>>(h1n, 128, W_pool1, 128,
                                           nullptr, 0, nullptr, 0,
                                           b_pool1, p1, 128, 128, 1, nullptr, nullptr);
  segmax_k<<<4096, 128, 0, stream>>>(p1, rowptr, eidx, hn1, 128);
  gemm_nt<<<dim3(2, 64), blk, 0, stream>>>(h1n, 128, W_self1, 128,
                                           hn1, 128, W_neigh1, 128,
                                           b1, h2, 128, 128, 0, nullptr, nullptr);

  // SMOTE
  gemm_nt<<<dim3(16, 16), blk, 0, stream>>>(h2, 128, h2, 128,
                                            nullptr, 0, nullptr, 0,
                                            nullptr, dots, 1024, 128, 0, nullptr, nullptr);
  sqn_k<<<1024, 128, 0, stream>>>(h2, sqn);
  argmin_k<<<1024, 256, 0, stream>>>(dots, sqn, nn);
  // dots dead now -> clear bitmap in its place
  hipMemsetAsync(bitmap, 0, 524288 * 4, stream);
  build_x_k<<<6144, 128, 0, stream>>>(h2, nn, gaps, x);
  conv_xt_k<<<dim3(96, 2), blk, 0, stream>>>(x, xt);

  // decoder gemm writes bf16 directly
  gemm_nt<<<dim3(2, 96), blk, 0, stream>>>(x, 128, de_w, 128,
                                           nullptr, 0, nullptr, 0,
                                           nullptr, nullptr, 128, 128, 0, ob, nullptr);
  // sparse loss correction (dedup via bitmap), then dense fused pass (no adj)
  edge_claim_k<<<256, blk, 0, stream>>>(src, dst, ob, bitmap, scal, E);
  fused_mfma<<<dim3(96, 8), blk, 0, stream>>>(ob, xt, neigh, rowsum, scal, 12);

  // classifier: neigh/(rowsum+1) folded into the gemm's A2 path
  gemm_nt<<<dim3(2, 96), blk, 0, stream>>>(x, 128, W_conv, 256,
                                           neigh, 128, W_conv + 128, 256,
                                           nullptr, hc, 128, 128, 0, nullptr, rowsum);
  logits_y_loss_k<<<6144, 128, 0, stream>>>(hc, W_clf, b_clf, labels, scal, outp);

  (void)n_in; (void)out_size; (void)ws_size; (void)in_sizes;
}

// Round 4
// 431.379 us; speedup vs baseline: 1.1866x; 1.1866x over previous
//
#include <hip/hip_runtime.h>
#include <cstddef>

typedef unsigned short ushort_t;
typedef __attribute__((ext_vector_type(8))) short bf16x8;
typedef __attribute__((ext_vector_type(4))) float f32x4;

// ---------------- workspace layout (float offsets) ----------------
// [0..1048576): p0 (4096x256) -> dots (1024x1024) -> bitmap (524288 words, 2MB)
#define WS_P0     0u
#define WS_DOTS   0u
#define WS_BITMAP 0u
#define WS_HN0    1048576u   /* 4096x256; -> hc (6144x128) at the end */
#define WS_HC     1048576u
#define WS_H1     2097152u   /* 4096x128 */
#define WS_H1N    2621440u   /* 4096x128 */
#define WS_P1     3145728u   /* 4096x128; -> xt (bf16 128x6144 = 393216 f) */
#define WS_XT     3145728u
#define WS_HN1    3670016u   /* 4096x128; -> sqn (1024) after h2 gemm */
#define WS_SQN    3670016u
#define WS_H2     4194304u   /* 4096x128; -> elist (int2 x 69632) after build_x */
#define WS_ELIST  4194304u
#define WS_X      4718592u   /* 6144x128 */
#define WS_OB     5505024u   /* bf16 6144x128 = 393216 floats */
// ---- contiguous zero region (one memset): ----
#define WS_NEIGH  6291456u   /* 786432 */
#define WS_ROWSUM 7077888u   /* 6144 */
#define WS_SCAL   7084032u   /* 16 floats: [S_all, s1, -, sub]; int ecount at +4 */
#define WS_DEG    7084048u   /* int 4096 */
// ---- end zero region ----
#define WS_NN     7088144u   /* int 1024 */
#define WS_CUR    7089168u   /* int 4096 */
#define WS_ROWPTR 7093264u   /* int 4097 */
#define WS_EIDX   7097361u   /* int 69632 */

__device__ inline ushort_t f2bf(float f) {
  unsigned u = __float_as_uint(f);
  u += 0x7fff + ((u >> 16) & 1);   // round-to-nearest-even
  return (ushort_t)(u >> 16);
}

// ---------------- generic NT GEMM: C = act(A@B^T (+ A2@B2^T) + bias) -------
__global__ __launch_bounds__(256, 2) void gemm_nt(
    const float* __restrict__ A, int lda,
    const float* __restrict__ B, int ldb,
    const float* __restrict__ A2, int lda2,
    const float* __restrict__ B2, int ldb2,
    const float* __restrict__ bias,
    float* __restrict__ C, int ldc,
    int K, int relu,
    ushort_t* __restrict__ Cb,
    const float* __restrict__ a2scale)
{
  __shared__ float As[16][68];
  __shared__ float Bs[16][68];
  const int tid = threadIdx.x;
  const int tx = tid & 15, ty = tid >> 4;
  const int lr = tid >> 2;
  const int lk = (tid & 3) << 2;
  const int i0 = blockIdx.y << 6;
  const int j0 = blockIdx.x << 6;
  float acc[4][4] = {};
  const int npass = (A2 != nullptr) ? 2 : 1;
  for (int pass = 0; pass < npass; ++pass) {
    const float* Ap = pass ? A2 : A; const int la = pass ? lda2 : lda;
    const float* Bp = pass ? B2 : B; const int lb = pass ? ldb2 : ldb;
    const float sc = (pass && a2scale) ? __frcp_rn(a2scale[i0 + lr] + 1.f) : 1.f;
    for (int k0 = 0; k0 < K; k0 += 16) {
      float4 ag = *(const float4*)(Ap + (size_t)(i0 + lr) * la + (k0 + lk));
      const float4 bg = *(const float4*)(Bp + (size_t)(j0 + lr) * lb + (k0 + lk));
      ag.x *= sc; ag.y *= sc; ag.z *= sc; ag.w *= sc;
      __syncthreads();
      As[lk+0][lr]=ag.x; As[lk+1][lr]=ag.y; As[lk+2][lr]=ag.z; As[lk+3][lr]=ag.w;
      Bs[lk+0][lr]=bg.x; Bs[lk+1][lr]=bg.y; Bs[lk+2][lr]=bg.z; Bs[lk+3][lr]=bg.w;
      __syncthreads();
#pragma unroll
      for (int k = 0; k < 16; ++k) {
        const float4 a4 = *(const float4*)&As[k][ty << 2];
        const float4 b4 = *(const float4*)&Bs[k][tx << 2];
        const float aa[4] = {a4.x, a4.y, a4.z, a4.w};
        const float bb[4] = {b4.x, b4.y, b4.z, b4.w};
#pragma unroll
        for (int ii = 0; ii < 4; ++ii)
#pragma unroll
          for (int jj = 0; jj < 4; ++jj)
            acc[ii][jj] += aa[ii] * bb[jj];
      }
    }
  }
  float badd[4] = {0.f, 0.f, 0.f, 0.f};
  if (bias) {
    const float4 t = *(const float4*)(bias + j0 + (tx << 2));
    badd[0]=t.x; badd[1]=t.y; badd[2]=t.z; badd[3]=t.w;
  }
#pragma unroll
  for (int ii = 0; ii < 4; ++ii) {
    float4 o;
    o.x = acc[ii][0] + badd[0];
    o.y = acc[ii][1] + badd[1];
    o.z = acc[ii][2] + badd[2];
    o.w = acc[ii][3] + badd[3];
    if (relu) { o.x=fmaxf(o.x,0.f); o.y=fmaxf(o.y,0.f); o.z=fmaxf(o.z,0.f); o.w=fmaxf(o.w,0.f); }
    const size_t off = (size_t)(i0 + (ty<<2) + ii) * ldc + j0 + (tx<<2);
    if (Cb) {
      ushort4 ob4;
      ob4.x = f2bf(o.x); ob4.y = f2bf(o.y); ob4.z = f2bf(o.z); ob4.w = f2bf(o.w);
      *(ushort4*)(Cb + off) = ob4;
    } else {
      *(float4*)(C + off) = o;
    }
  }
}

// ---------------- CSR build (bucket edges by dst) ----------------
__global__ void count_k(const int* __restrict__ dst, int* __restrict__ deg, int E) {
  const int e = blockIdx.x * 256 + threadIdx.x;
  if (e < E) atomicAdd(&deg[dst[e]], 1);
}

__global__ __launch_bounds__(1024) void scan_k(const int* __restrict__ deg,
                                               int* __restrict__ rowptr,
                                               int* __restrict__ cursor) {
  __shared__ int sums[1024];
  const int t = threadIdx.x;
  const int4 d = *(const int4*)(deg + (t << 2));
  const int local = d.x + d.y + d.z + d.w;
  sums[t] = local;
  __syncthreads();
  for (int off = 1; off < 1024; off <<= 1) {
    int v = (t >= off) ? sums[t - off] : 0;
    __syncthreads();
    sums[t] += v;
    __syncthreads();
  }
  const int excl = sums[t] - local;
  const int o0 = excl, o1 = o0 + d.x, o2 = o1 + d.y, o3 = o2 + d.z;
  rowptr[(t<<2)+0]=o0; rowptr[(t<<2)+1]=o1; rowptr[(t<<2)+2]=o2; rowptr[(t<<2)+3]=o3;
  cursor[(t<<2)+0]=o0; cursor[(t<<2)+1]=o1; cursor[(t<<2)+2]=o2; cursor[(t<<2)+3]=o3;
  if (t == 1023) rowptr[4096] = sums[1023];
}

__global__ void fill_k(const int* __restrict__ src, const int* __restrict__ dst,
                       int* __restrict__ cursor, int* __restrict__ eidx, int E) {
  const int e = blockIdx.x * 256 + threadIdx.x;
  if (e < E) {
    const int p = atomicAdd(&cursor[dst[e]], 1);
    eidx[p] = src[e];
  }
}

// segment_max as CSR gather. p >= 0 (relu'd) and every segment non-empty
// (self-loops), so init 0 reproduces the isfinite->0 semantics exactly.
__global__ void segmax_k(const float* __restrict__ p, const int* __restrict__ rowptr,
                         const int* __restrict__ eidx, float* __restrict__ hn, int F) {
  const int row = blockIdx.x, f = threadIdx.x;  // blockDim == F
  const int b = rowptr[row], e = rowptr[row + 1];
  float m = 0.f;
  for (int k = b; k < e; ++k) m = fmaxf(m, p[(size_t)eidx[k] * F + f]);
  hn[(size_t)row * F + f] = m;
}

// ---------------- small fused elementwise / reductions ----------------
__device__ inline float wave_sum(float v) {
#pragma unroll
  for (int o = 32; o > 0; o >>= 1) v += __shfl_down(v, o, 64);
  return v;
}

__global__ void relu_l2norm_k(const float* __restrict__ in, float* __restrict__ out) {
  const int row = blockIdx.x, f = threadIdx.x;  // 128 threads
  const float v = fmaxf(in[(size_t)row * 128 + f], 0.f);
  const float ss = wave_sum(v * v);
  __shared__ float w[2];
  if ((f & 63) == 0) w[f >> 6] = ss;
  __syncthreads();
  const float denom = fmaxf(sqrtf(w[0] + w[1]), 1e-12f);
  out[(size_t)row * 128 + f] = v / denom;
}

__global__ void sqn_k(const float* __restrict__ h2, float* __restrict__ sqn) {
  const int row = blockIdx.x, f = threadIdx.x;  // 128 threads
  const float v = h2[(size_t)row * 128 + f];
  const float ss = wave_sum(v * v);
  __shared__ float w[2];
  if ((f & 63) == 0) w[f >> 6] = ss;
  __syncthreads();
  if (f == 0) sqn[row] = w[0] + w[1];
}

// nearest neighbor (excluding self), tie-break smallest index = stable argsort pos 1
__global__ void argmin_k(const float* __restrict__ dots, const float* __restrict__ sqn,
                         int* __restrict__ nn) {
  const int i = blockIdx.x, tid = threadIdx.x;  // 256 threads
  float best = 3.402823466e38f; int bidx = 0x7fffffff;
  const float si = sqn[i];
  for (int j = tid; j < 1024; j += 256) {
    if (j == i) continue;
    float d2 = si + sqn[j] - 2.f * dots[(size_t)i * 1024 + j];
    d2 = fmaxf(d2, 0.f);
    if (d2 < best || (d2 == best && j < bidx)) { best = d2; bidx = j; }
  }
  __shared__ float bv[256]; __shared__ int bi[256];
  bv[tid] = best; bi[tid] = bidx;
  __syncthreads();
  for (int s = 128; s > 0; s >>= 1) {
    if (tid < s) {
      if (bv[tid+s] < bv[tid] || (bv[tid+s] == bv[tid] && bi[tid+s] < bi[tid])) {
        bv[tid] = bv[tid+s]; bi[tid] = bi[tid+s];
      }
    }
    __syncthreads();
  }
  if (tid == 0) nn[i] = bi[0];
}

__global__ void build_x_k(const float* __restrict__ h2, const int* __restrict__ nn,
                          const float* __restrict__ gaps, float* __restrict__ x) {
  const int row = blockIdx.x, f = threadIdx.x;  // 128 threads, grid 6144
  if (row < 4096) {
    x[(size_t)row * 128 + f] = h2[(size_t)row * 128 + f];
  } else {
    const int s = row - 4096, i = s >> 1, r = s & 1;
    const float g = gaps[(i << 1) + r];
    const float c  = h2[(size_t)i * 128 + f];
    const float cn = h2[(size_t)nn[i] * 128 + f];
    x[(size_t)row * 128 + f] = c + g * (cn - c);
  }
}

// x (6144x128 f32) -> xt (128x6144 bf16), 64x64 LDS tile transpose
__global__ void conv_xt_k(const float* __restrict__ x, ushort_t* __restrict__ xt) {
  __shared__ ushort_t t[64][65];
  const int i0 = blockIdx.x << 6, c0 = blockIdx.y << 6;
  const int il = threadIdx.x & 63, rl = threadIdx.x >> 6;
#pragma unroll
  for (int rr = 0; rr < 16; ++rr) {
    const int r = (rr << 2) + rl;
    t[r][il] = f2bf(x[(size_t)(i0 + r) * 128 + c0 + il]);
  }
  __syncthreads();
#pragma unroll
  for (int rr = 0; rr < 16; ++rr) {
    const int c = (rr << 2) + rl;
    xt[(size_t)(c0 + c) * 6144 + i0 + il] = t[il][c];
  }
}

// ---------------- edge path: compact distinct cells, then loss ----------------
__global__ void edge_compact_k(const int* __restrict__ src, const int* __restrict__ dst,
                               unsigned* __restrict__ bitmap, int2* __restrict__ elist,
                               int* __restrict__ ecount, int E) {
  const int e = blockIdx.x * 256 + threadIdx.x;
  const int lane = threadIdx.x & 63;
  int d_ = 0, s_ = 0, claimed = 0;
  if (e < E) {
    d_ = dst[e]; s_ = src[e];
    const unsigned cell = ((unsigned)d_ << 12) + (unsigned)s_;
    const unsigned bit = 1u << (cell & 31);
    const unsigned old = atomicOr(&bitmap[cell >> 5], bit);
    claimed = !(old & bit);
  }
  const unsigned long long m = __ballot(claimed);
  int base = 0;
  if (lane == 0 && m) base = atomicAdd(ecount, (int)__popcll(m));
  base = __shfl(base, 0, 64);
  if (claimed) {
    const int pos = base + (int)__popcll(m & ((1ull << lane) - 1ull));
    elist[pos] = make_int2(d_, s_);
  }
}

// one wave per distinct edge (strided): s1 += (sg-1)^2, sub += sg^2
__global__ __launch_bounds__(256) void edge_loss_k(
    const int2* __restrict__ elist, const int* __restrict__ ecount,
    const ushort_t* __restrict__ ob, float* __restrict__ scal) {
  __shared__ float part[2];
  const int tid = threadIdx.x;
  if (tid < 2) part[tid] = 0.f;
  __syncthreads();
  const int lane = tid & 63;
  const int n = *ecount;
  const int nw = gridDim.x << 2;
  float p1 = 0.f, psub = 0.f;
  for (int e = (blockIdx.x << 2) + (tid >> 6); e < n; e += nw) {
    const int2 ed = elist[e];
    const unsigned a = *(const unsigned*)(ob + ((size_t)ed.x << 7) + (lane << 1));
    const unsigned b = *(const unsigned*)(ob + ((size_t)ed.y << 7) + (lane << 1));
    const float a0 = __uint_as_float(a << 16), a1 = __uint_as_float(a & 0xffff0000u);
    const float b0 = __uint_as_float(b << 16), b1 = __uint_as_float(b & 0xffff0000u);
    float v = a0 * b0 + a1 * b1;
    v = wave_sum(v);
    if (lane == 0) {
      const float sg = 1.f / (1.f + __expf(-v));
      p1 += (sg - 1.f) * (sg - 1.f);
      psub += sg * sg;
    }
  }
  if (lane == 0) { atomicAdd(&part[0], p1); atomicAdd(&part[1], psub); }
  __syncthreads();
  if (tid == 0) { atomicAdd(&scal[1], part[0]); atomicAdd(&scal[3], part[1]); }
}

// ---------------- fused MFMA v3: pipelined, shared-panel ----------------
// grid (96, 8), block 256 (4 waves). Block owns 64 i-rows; wave w owns the full
// 64 i-rows (A-frags persistent in regs) and j-strip [w*16,w*16+16) of each
// 64-wide j-tile for S. xt tiles double-buffered in LDS (staged once/block).
// PV of tile jt-1 overlaps the global loads of tile jt.
__global__ __launch_bounds__(256) void fused_mfma(
    const ushort_t* __restrict__ ob,   // 6144x128 bf16 (out)
    const ushort_t* __restrict__ xt,   // 128x6144 bf16 (x transposed)
    float* __restrict__ neigh,         // 6144x128, pre-zeroed
    float* __restrict__ rowsum,        // 6144, pre-zeroed
    float* __restrict__ scal,          // [S_all, s1, -, sub], pre-zeroed
    int njt)
{
  __shared__ ushort_t xtS[2][128][72];   // 36 KB, padded rows (144B) vs banks
  __shared__ ushort_t P[64][72];         // 9 KB
  __shared__ float red[256];
  const int tid = threadIdx.x;
  const int w = tid >> 6, lane = tid & 63;
  const int lo = lane & 15, hi = lane >> 4;
  const int i0 = blockIdx.x << 6;
  const int jt0 = blockIdx.y * njt;
  const bool i_ok = (blockIdx.x < 64);

  // A-fragments: 4 i-tiles x 4 k, persistent across the whole j-loop
  bf16x8 ao[4][4];
#pragma unroll
  for (int t = 0; t < 4; ++t) {
    const ushort_t* ap = ob + (size_t)(i0 + (t << 4) + lo) * 128 + (hi << 3);
#pragma unroll
    for (int k = 0; k < 4; ++k) ao[t][k] = *(const bf16x8*)(ap + (k << 5));
  }
  f32x4 oacc[4][2];
#pragma unroll
  for (int t = 0; t < 4; ++t)
#pragma unroll
    for (int sl = 0; sl < 2; ++sl) oacc[t][sl] = (f32x4){0.f, 0.f, 0.f, 0.f};
  float rs[4][4] = {};
  float s_all = 0.f;

  const int srow = tid >> 1, scol = (tid & 1) << 5;  // staging: 128 rows x 2 halves
  int4 sreg[4];
  // prologue: stage tile 0 into xtS[0]
  {
    const ushort_t* sp = xt + (size_t)srow * 6144 + (jt0 << 6) + scol;
#pragma unroll
    for (int i = 0; i < 4; ++i) sreg[i] = *(const int4*)(sp + (i << 3));
    ushort_t* dp = &xtS[0][srow][scol];
#pragma unroll
    for (int i = 0; i < 4; ++i) *(int4*)(dp + (i << 3)) = sreg[i];
  }
  __syncthreads();

  for (int jt = 0; jt < njt; ++jt) {
    const int nxt = (jt & 1) ^ 1;        // == (jt-1)&1 == (jt+1)&1
    const int j0 = (jt0 + jt) << 6;
    const bool j_ok = (jt0 + jt) < 64;
    // prefetch next xt tile to regs (latency hidden by PV below)
    if (jt + 1 < njt) {
      const ushort_t* sp = xt + (size_t)srow * 6144 + (j0 + 64) + scol;
#pragma unroll
      for (int i = 0; i < 4; ++i) sreg[i] = *(const int4*)(sp + (i << 3));
    }
    // B-fragments for current tile: wave w's 16 j-rows (panel read once/block)
    bf16x8 bf[4];
    {
      const ushort_t* bp = ob + (size_t)(j0 + (w << 4) + lo) * 128 + (hi << 3);
#pragma unroll
      for (int k = 0; k < 4; ++k) bf[k] = *(const bf16x8*)(bp + (k << 5));
    }
    // ---- PV for previous tile (xtS[nxt], P) — overlaps the loads above ----
    if (jt > 0) {
      bf16x8 xb[2][2];
#pragma unroll
      for (int sl = 0; sl < 2; ++sl) {
        const ushort_t* xp = &xtS[nxt][((w << 1) + sl) << 4][hi << 3];
        xb[sl][0] = *(const bf16x8*)(xp + (size_t)lo * 72);
        xb[sl][1] = *(const bf16x8*)(xp + (size_t)lo * 72 + 32);
      }
#pragma unroll
      for (int t = 0; t < 4; ++t) {
        const bf16x8 pa0 = *(const bf16x8*)&P[(t << 4) + lo][hi << 3];
        const bf16x8 pa1 = *(const bf16x8*)&P[(t << 4) + lo][32 + (hi << 3)];
#pragma unroll
        for (int sl = 0; sl < 2; ++sl) {
          oacc[t][sl] = __builtin_amdgcn_mfma_f32_16x16x32_bf16(pa0, xb[sl][0], oacc[t][sl], 0, 0, 0);
          oacc[t][sl] = __builtin_amdgcn_mfma_f32_16x16x32_bf16(pa1, xb[sl][1], oacc[t][sl], 0, 0, 0);
        }
      }
    }
    __syncthreads();
    // write staged regs for NEXT tile into the buffer PV just finished with
    if (jt + 1 < njt) {
      ushort_t* dp = &xtS[nxt][srow][scol];
#pragma unroll
      for (int i = 0; i < 4; ++i) *(int4*)(dp + (i << 3)) = sreg[i];
    }
    // ---- S for current tile: rows = all 64 i, cols = wave's 16 j ----
#pragma unroll
    for (int t = 0; t < 4; ++t) {
      f32x4 sacc = (f32x4){0.f, 0.f, 0.f, 0.f};
#pragma unroll
      for (int k = 0; k < 4; ++k)
        sacc = __builtin_amdgcn_mfma_f32_16x16x32_bf16(ao[t][k], bf[k], sacc, 0, 0, 0);
#pragma unroll
      for (int r = 0; r < 4; ++r) {
        const float sg = 1.f / (1.f + __expf(-sacc[r]));
        if (i_ok && j_ok) s_all += sg * sg;
        const float th = (sg >= 0.5f) ? sg : 0.f;
        rs[t][r] += th;
        P[(t << 4) + (hi << 2) + r][(w << 4) + lo] = f2bf(th);
      }
    }
    __syncthreads();   // P complete for all waves before next iter's PV
  }
  // final PV for tile njt-1
  {
    const int buf = (njt - 1) & 1;
    bf16x8 xb[2][2];
#pragma unroll
    for (int sl = 0; sl < 2; ++sl) {
      const ushort_t* xp = &xtS[buf][((w << 1) + sl) << 4][hi << 3];
      xb[sl][0] = *(const bf16x8*)(xp + (size_t)lo * 72);
      xb[sl][1] = *(const bf16x8*)(xp + (size_t)lo * 72 + 32);
    }
#pragma unroll
    for (int t = 0; t < 4; ++t) {
      const bf16x8 pa0 = *(const bf16x8*)&P[(t << 4) + lo][hi << 3];
      const bf16x8 pa1 = *(const bf16x8*)&P[(t << 4) + lo][32 + (hi << 3)];
#pragma unroll
      for (int sl = 0; sl < 2; ++sl) {
        oacc[t][sl] = __builtin_amdgcn_mfma_f32_16x16x32_bf16(pa0, xb[sl][0], oacc[t][sl], 0, 0, 0);
        oacc[t][sl] = __builtin_amdgcn_mfma_f32_16x16x32_bf16(pa1, xb[sl][1], oacc[t][sl], 0, 0, 0);
      }
    }
  }
  // ---- rowsum flush: reduce each rs over the 16 lo-lanes ----
#pragma unroll
  for (int t = 0; t < 4; ++t)
#pragma unroll
    for (int r = 0; r < 4; ++r) {
      float v = rs[t][r];
#pragma unroll
      for (int m = 1; m < 16; m <<= 1) v += __shfl_xor(v, m, 64);
      if (lo == 0) atomicAdd(&rowsum[i0 + (t << 4) + (hi << 2) + r], v);
    }
  // ---- neigh flush (8 j-chunks accumulate) ----
#pragma unroll
  for (int t = 0; t < 4; ++t)
#pragma unroll
    for (int sl = 0; sl < 2; ++sl)
#pragma unroll
      for (int r = 0; r < 4; ++r)
        atomicAdd(&neigh[(size_t)(i0 + (t << 4) + (hi << 2) + r) * 128 +
                         (((w << 1) + sl) << 4) + lo], oacc[t][sl][r]);
  // ---- S_all block reduction ----
  red[tid] = s_all; __syncthreads();
  for (int s = 128; s > 0; s >>= 1) { if (tid < s) red[tid] += red[tid + s]; __syncthreads(); }
  if (tid == 0) atomicAdd(&scal[0], red[0]);
}

// logits + y + final loss in one launch
__global__ void logits_y_loss_k(const float* __restrict__ hc, const float* __restrict__ Wclf,
                                const float* __restrict__ bclf, const int* __restrict__ labels,
                                const float* __restrict__ scal, const int* __restrict__ ecount,
                                float* __restrict__ outp) {
  const int i = blockIdx.x, f = threadIdx.x;  // 128 threads
  const float h = hc[(size_t)i * 128 + f];
  const float v0 = wave_sum(h * Wclf[f]);
  const float v1 = wave_sum(h * Wclf[128 + f]);
  __shared__ float w0[2], w1[2];
  if ((f & 63) == 0) { w0[f >> 6] = v0; w1[f >> 6] = v1; }
  __syncthreads();
  if (f == 0) {
    outp[(size_t)i * 2 + 0] = w0[0] + w0[1] + bclf[0];
    outp[(size_t)i * 2 + 1] = w1[0] + w1[1] + bclf[1];
    outp[12288 + i] = (i < 4096) ? (float)labels[i] : 1.f;
    if (i == 0) {
      const float cnt = (float)(*ecount);
      const float neg_w = cnt / (16777216.f - cnt);
      outp[18432] = neg_w * (scal[0] - scal[3]) + scal[1];
    }
  }
}

// ---------------- launcher ----------------
extern "C" void kernel_launch(void* const* d_in, const int* in_sizes, int n_in,
                              void* d_out, int out_size, void* d_ws, size_t ws_size,
                              hipStream_t stream) {
  const float* feat     = (const float*)d_in[0];
  const int*   src      = (const int*)d_in[2];
  const int*   dst      = (const int*)d_in[3];
  const int*   labels   = (const int*)d_in[4];
  const float* W_pool0  = (const float*)d_in[5];
  const float* b_pool0  = (const float*)d_in[6];
  const float* W_self0  = (const float*)d_in[7];
  const float* W_neigh0 = (const float*)d_in[8];
  const float* b0       = (const float*)d_in[9];
  const float* W_pool1  = (const float*)d_in[10];
  const float* b_pool1  = (const float*)d_in[11];
  const float* W_self1  = (const float*)d_in[12];
  const float* W_neigh1 = (const float*)d_in[13];
  const float* b1       = (const float*)d_in[14];
  const float* de_w     = (const float*)d_in[15];
  const float* W_conv   = (const float*)d_in[16];
  const float* W_clf    = (const float*)d_in[17];
  const float* b_clf    = (const float*)d_in[18];
  const float* gaps     = (const float*)d_in[19];
  const int E = in_sizes[2];  // 69632 (E + self-loops)

  float* ws = (float*)d_ws;
  float* p0       = ws + WS_P0;
  float* dots     = ws + WS_DOTS;
  unsigned* bitmap= (unsigned*)(ws + WS_BITMAP);
  float* hn0      = ws + WS_HN0;
  float* hc       = ws + WS_HC;
  float* h1       = ws + WS_H1;
  float* h1n      = ws + WS_H1N;
  float* p1       = ws + WS_P1;
  ushort_t* xt    = (ushort_t*)(ws + WS_XT);
  float* hn1      = ws + WS_HN1;
  float* sqn      = ws + WS_SQN;
  float* h2       = ws + WS_H2;
  int2* elist     = (int2*)(ws + WS_ELIST);
  float* x        = ws + WS_X;
  ushort_t* ob    = (ushort_t*)(ws + WS_OB);
  float* neigh    = ws + WS_NEIGH;
  float* rowsum   = ws + WS_ROWSUM;
  float* scal     = ws + WS_SCAL;
  int* ecount     = (int*)(ws + WS_SCAL + 4);
  int* deg        = (int*)(ws + WS_DEG);
  int* nn         = (int*)(ws + WS_NN);
  int* cursor     = (int*)(ws + WS_CUR);
  int* rowptr     = (int*)(ws + WS_ROWPTR);
  int* eidx       = (int*)(ws + WS_EIDX);

  float* outp = (float*)d_out;
  const dim3 blk(256);

  // one contiguous zero region: neigh + rowsum + scal(+ecount) + deg
  hipMemsetAsync(neigh, 0, (size_t)(WS_DEG + 4096 - WS_NEIGH) * 4, stream);

  // CSR bucket-by-dst
  count_k<<<(E + 255) / 256, blk, 0, stream>>>(dst, deg, E);
  scan_k<<<1, 1024, 0, stream>>>(deg, rowptr, cursor);
  fill_k<<<(E + 255) / 256, blk, 0, stream>>>(src, dst, cursor, eidx, E);

  // layer 0
  gemm_nt<<<dim3(4, 64), blk, 0, stream>>>(feat, 256, W_pool0, 256,
                                           nullptr, 0, nullptr, 0,
                                           b_pool0, p0, 256, 256, 1, nullptr, nullptr);
  segmax_k<<<4096, 256, 0, stream>>>(p0, rowptr, eidx, hn0, 256);
  gemm_nt<<<dim3(2, 64), blk, 0, stream>>>(feat, 256, W_self0, 256,
                                           hn0, 256, W_neigh0, 256,
                                           b0, h1, 128, 256, 0, nullptr, nullptr);
  relu_l2norm_k<<<4096, 128, 0, stream>>>(h1, h1n);

  // layer 1
  gemm_nt<<<dim3(2, 64), blk, 0, stream>>>(h1n, 128, W_pool1, 128,
                                           nullptr, 0, nullptr, 0,
                                           b_pool1, p1, 128, 128, 1, nullptr, nullptr);
  segmax_k<<<4096, 128, 0, stream>>>(p1, rowptr, eidx, hn1, 128);
  gemm_nt<<<dim3(2, 64), blk, 0, stream>>>(h1n, 128, W_self1, 128,
                                           hn1, 128, W_neigh1, 128,
                                           b1, h2, 128, 128, 0, nullptr, nullptr);

  // SMOTE
  gemm_nt<<<dim3(16, 16), blk, 0, stream>>>(h2, 128, h2, 128,
                                            nullptr, 0, nullptr, 0,
                                            nullptr, dots, 1024, 128, 0, nullptr, nullptr);
  sqn_k<<<1024, 128, 0, stream>>>(h2, sqn);
  argmin_k<<<1024, 256, 0, stream>>>(dots, sqn, nn);
  // dots dead now -> clear bitmap in its place
  hipMemsetAsync(bitmap, 0, 524288 * 4, stream);
  build_x_k<<<6144, 128, 0, stream>>>(h2, nn, gaps, x);
  conv_xt_k<<<dim3(96, 2), blk, 0, stream>>>(x, xt);
  // h2 dead now -> elist lives there; compact distinct adj cells
  edge_compact_k<<<(E + 255) / 256, blk, 0, stream>>>(src, dst, bitmap, elist, ecount, E);

  // decoder gemm writes bf16 directly
  gemm_nt<<<dim3(2, 96), blk, 0, stream>>>(x, 128, de_w, 128,
                                           nullptr, 0, nullptr, 0,
                                           nullptr, nullptr, 128, 128, 0, ob, nullptr);
  // sparse loss over distinct edges, then dense fused pass (no adj anywhere)
  edge_loss_k<<<768, blk, 0, stream>>>(elist, ecount, ob, scal);
  fused_mfma<<<dim3(96, 8), blk, 0, stream>>>(ob, xt, neigh, rowsum, scal, 12);

  // classifier: neigh/(rowsum+1) folded into the gemm's A2 path
  gemm_nt<<<dim3(2, 96), blk, 0, stream>>>(x, 128, W_conv, 256,
                                           neigh, 128, W_conv + 128, 256,
                                           nullptr, hc, 128, 128, 0, nullptr, rowsum);
  logits_y_loss_k<<<6144, 128, 0, stream>>>(hc, W_clf, b_clf, labels, scal, ecount, outp);

  (void)n_in; (void)out_size; (void)ws_size; (void)in_sizes;
}